// Round 5
// baseline (180.628 us; speedup 1.0000x reference)
//
#include <hip/hip_runtime.h>
#include <cmath>

// ---------- types & helpers ----------
typedef __attribute__((ext_vector_type(8))) __bf16 bf16x8;
typedef __attribute__((ext_vector_type(8))) unsigned short ushort8v;
typedef __attribute__((ext_vector_type(4))) float f32x4;

__device__ inline unsigned short f2bf(float f) {
    unsigned int u = __float_as_uint(f);
    unsigned int r = (u + 0x7fffu + ((u >> 16) & 1u)) >> 16;   // RNE
    return (unsigned short)r;
}

__device__ inline bf16x8 ld8(const unsigned short* p) {
    uint4 v = *(const uint4*)p;
    return __builtin_bit_cast(bf16x8, v);
}

__device__ inline f32x4 mfma16(bf16x8 a, bf16x8 b, f32x4 c) {
    return __builtin_amdgcn_mfma_f32_16x16x32_bf16(a, b, c, 0, 0, 0);
}

// truncating pack: low16 = hi16(a), high16 = hi16(b)  (1 v_perm_b32)
__device__ inline unsigned pk2t(float a, float b) {
    return __builtin_amdgcn_perm(__float_as_uint(b), __float_as_uint(a), 0x07060302u);
}

// async global->LDS, 16B per lane.
__device__ inline void gl_lds16(const unsigned short* g, const unsigned short* l) {
    __builtin_amdgcn_global_load_lds(
        (const __attribute__((address_space(1))) void*)(unsigned long long)g,
        (__attribute__((address_space(3))) void*)(unsigned)(unsigned long long)l,
        16, 0, 0);
}

// ---------- fused fp32 -> bf16 convert ----------
#define NX4  1048576   // M*E/4
#define NW14 786432    // N1*E/4
#define NW24 262144    // E*E/4
__global__ __launch_bounds__(256) void cvt3(const float* __restrict__ x,
                                            const float* __restrict__ w1,
                                            const float* __restrict__ w2,
                                            unsigned short* __restrict__ xb,
                                            unsigned short* __restrict__ w1b,
                                            unsigned short* __restrict__ w2b) {
    int i = blockIdx.x * 256 + threadIdx.x;
    const float* src;
    unsigned short* dst;
    int off;
    if (i < NX4)              { src = x;  dst = xb;  off = i; }
    else if (i < NX4 + NW14)  { src = w1; dst = w1b; off = i - NX4; }
    else                      { src = w2; dst = w2b; off = i - NX4 - NW14; }
    float4 v = ((const float4*)src)[off];
    ushort4 o;
    o.x = f2bf(v.x); o.y = f2bf(v.y); o.z = f2bf(v.z); o.w = f2bf(v.w);
    ((ushort4*)dst)[off] = o;
}

// ---------- out-proj GEMM: C[M,N] = A@B^T + bias, fp32 out ----------
__global__ __launch_bounds__(256) void gemm_out(const unsigned short* __restrict__ A,
                                                const unsigned short* __restrict__ B,
                                                const float* __restrict__ bias,
                                                float* __restrict__ C,
                                                int M, int N, int K) {
    __shared__ __align__(16) unsigned short As0[64 * 32];
    __shared__ __align__(16) unsigned short Bs0[128 * 32];
    __shared__ __align__(16) unsigned short As1[64 * 32];
    __shared__ __align__(16) unsigned short Bs1[128 * 32];
    const int m0 = blockIdx.y * 64;
    const int n0 = blockIdx.x * 128;
    const int t = threadIdx.x;
    const int wave = t >> 6, lane = t & 63;
    const int l16 = lane & 15, quad = lane >> 4;
    const int wm = (wave >> 1) * 32, wn = (wave & 1) * 64;

    f32x4 acc[2][4] = {};

    const int ra = t >> 2, ka = (t & 3) * 8;
    const int b1 = 256 + t;
    const int rb0 = t >> 2, kb0 = (t & 3) * 8;
    const int rb1 = b1 >> 2, kb1 = (b1 & 3) * 8;

    for (int k0 = 0; k0 < K; k0 += 64) {
        __syncthreads();
        gl_lds16(A + (size_t)(m0 + ra) * K + k0 + ka,        As0 + t * 8);
        gl_lds16(B + (size_t)(n0 + rb0) * K + k0 + kb0,      Bs0 + t * 8);
        gl_lds16(B + (size_t)(n0 + rb1) * K + k0 + kb1,      Bs0 + b1 * 8);
        gl_lds16(A + (size_t)(m0 + ra) * K + k0 + 32 + ka,   As1 + t * 8);
        gl_lds16(B + (size_t)(n0 + rb0) * K + k0 + 32 + kb0, Bs1 + t * 8);
        gl_lds16(B + (size_t)(n0 + rb1) * K + k0 + 32 + kb1, Bs1 + b1 * 8);
        __syncthreads();

        bf16x8 af[2], bfr[4];
        #pragma unroll
        for (int i = 0; i < 2; ++i)
            af[i] = ld8(As0 + (wm + i * 16 + l16) * 32 + quad * 8);
        #pragma unroll
        for (int j = 0; j < 4; ++j)
            bfr[j] = ld8(Bs0 + (wn + j * 16 + l16) * 32 + quad * 8);
        #pragma unroll
        for (int i = 0; i < 2; ++i)
            #pragma unroll
            for (int j = 0; j < 4; ++j)
                acc[i][j] = mfma16(af[i], bfr[j], acc[i][j]);

        #pragma unroll
        for (int i = 0; i < 2; ++i)
            af[i] = ld8(As1 + (wm + i * 16 + l16) * 32 + quad * 8);
        #pragma unroll
        for (int j = 0; j < 4; ++j)
            bfr[j] = ld8(Bs1 + (wn + j * 16 + l16) * 32 + quad * 8);
        #pragma unroll
        for (int i = 0; i < 2; ++i)
            #pragma unroll
            for (int j = 0; j < 4; ++j)
                acc[i][j] = mfma16(af[i], bfr[j], acc[i][j]);
    }

    #pragma unroll
    for (int i = 0; i < 2; ++i) {
        #pragma unroll
        for (int j = 0; j < 4; ++j) {
            int col = n0 + wn + j * 16 + l16;
            float bv = bias[col];
            #pragma unroll
            for (int r = 0; r < 4; ++r) {
                int row = m0 + wm + i * 16 + quad * 4 + r;
                C[(size_t)row * N + col] = acc[i][j][r] + bv;
            }
        }
    }
}

// ---------- QKV GEMM: 256x256 tile, 8-phase counted-vmcnt schedule (T2+T3+T4+T5) ----------
// (unchanged from best-measured round-3/4 version)
__global__ __launch_bounds__(512, 1) void gemm_qkv(const unsigned short* __restrict__ A,
                                                   const unsigned short* __restrict__ B,
                                                   const float* __restrict__ bias,
                                                   unsigned short* __restrict__ qp,
                                                   unsigned short* __restrict__ kvp,
                                                   int M, int N, int K) {
    __shared__ __align__(16) unsigned short L_[65536];   // 128 KB
    const int m0 = blockIdx.y * 256;
    const int n0 = blockIdx.x * 256;
    const int t = threadIdx.x;
    const int wave = t >> 6, lane = t & 63;
    const int l16 = lane & 15, quad = lane >> 4;
    const int wr = wave >> 2, wc = wave & 3;
    const int rswz = (l16 & 7) << 3;     // read-side chunk XOR (elements)

    f32x4 acc[8][4] = {};
    bf16x8 bf[4][2];

    // staging geometry: chunk c -> row c>>3, k-chunk (c&7) XOR (row&7) (pre-swizzled source)
    const int c0 = t, c1 = 512 + t;
    const int r0 = c0 >> 3, k0e = ((c0 & 7) ^ (r0 & 7)) * 8;
    const int r1 = c1 >> 3, k1e = ((c1 & 7) ^ (r1 & 7)) * 8;
    const unsigned short* Ab0 = A + (size_t)(m0 + r0) * 1024 + k0e;
    const unsigned short* Ab1 = A + (size_t)(m0 + r1) * 1024 + k1e;
    const unsigned short* Bb0 = B + (size_t)(n0 + r0) * 1024 + k0e;
    const unsigned short* Bb1 = B + (size_t)(n0 + r1) * 1024 + k1e;
    unsigned short* Ld0 = L_ + c0 * 8;
    unsigned short* Ld1 = L_ + c1 * 8;

#define STG_A(par, h, T_) do { \
    gl_lds16(Ab0 + (h) * 131072 + (T_) * 64, Ld0 + (par) * 16384 + (h) * 8192); \
    gl_lds16(Ab1 + (h) * 131072 + (T_) * 64, Ld1 + (par) * 16384 + (h) * 8192); } while (0)
#define STG_B(par, h, T_) do { \
    gl_lds16(Bb0 + (h) * 131072 + (T_) * 64, Ld0 + 32768 + (par) * 16384 + (h) * 8192); \
    gl_lds16(Bb1 + (h) * 131072 + (T_) * 64, Ld1 + 32768 + (par) * 16384 + (h) * 8192); } while (0)

    // fragment read bases (swizzled reads)
    const unsigned short* Afr = L_ + wr * 8192 + l16 * 64;
    const unsigned short* Bfr = L_ + 32768 + (wc >> 1) * 8192 + ((wc & 1) * 64 + l16) * 64;
    const int koff0 = (quad * 8) ^ rswz;
    const int koff1 = (32 + quad * 8) ^ rswz;

#define LDA0(dst, par, i_) dst = ld8(Afr + (par) * 16384 + (i_) * 1024 + koff0)
#define LDA1(dst, par, i_) dst = ld8(Afr + (par) * 16384 + (i_) * 1024 + koff1)
#define LDB0(dst, par, j_) dst = ld8(Bfr + (par) * 16384 + (j_) * 1024 + koff0)
#define LDB1(dst, par, j_) dst = ld8(Bfr + (par) * 16384 + (j_) * 1024 + koff1)

#define FEN() asm volatile("" ::: "memory")
#define BARR() do { FEN(); __builtin_amdgcn_s_barrier(); FEN(); } while (0)
#define VM4 asm volatile("s_waitcnt vmcnt(4)" ::: "memory")
#define VM0 asm volatile("s_waitcnt vmcnt(0)" ::: "memory")
#define VMN ((void)0)

#define PHASE(PAR, I0, LOADB, STG, VM) do { \
    bf16x8 a00, a01, a10, a11; \
    if (LOADB) { \
        LDB0(bf[0][0], PAR, 0); LDB1(bf[0][1], PAR, 0); \
        LDB0(bf[1][0], PAR, 1); LDB1(bf[1][1], PAR, 1); \
        LDB0(bf[2][0], PAR, 2); LDB1(bf[2][1], PAR, 2); \
        LDB0(bf[3][0], PAR, 3); LDB1(bf[3][1], PAR, 3); \
    } \
    LDA0(a00, PAR, I0); LDA1(a01, PAR, I0); \
    LDA0(a10, PAR, (I0) + 1); LDA1(a11, PAR, (I0) + 1); \
    STG; \
    BARR(); \
    __builtin_amdgcn_s_setprio(1); \
    acc[I0][0] = mfma16(a00, bf[0][0], acc[I0][0]); \
    acc[I0][1] = mfma16(a00, bf[1][0], acc[I0][1]); \
    acc[I0][2] = mfma16(a00, bf[2][0], acc[I0][2]); \
    acc[I0][3] = mfma16(a00, bf[3][0], acc[I0][3]); \
    acc[(I0)+1][0] = mfma16(a10, bf[0][0], acc[(I0)+1][0]); \
    acc[(I0)+1][1] = mfma16(a10, bf[1][0], acc[(I0)+1][1]); \
    acc[(I0)+1][2] = mfma16(a10, bf[2][0], acc[(I0)+1][2]); \
    acc[(I0)+1][3] = mfma16(a10, bf[3][0], acc[(I0)+1][3]); \
    acc[I0][0] = mfma16(a01, bf[0][1], acc[I0][0]); \
    acc[I0][1] = mfma16(a01, bf[1][1], acc[I0][1]); \
    acc[I0][2] = mfma16(a01, bf[2][1], acc[I0][2]); \
    acc[I0][3] = mfma16(a01, bf[3][1], acc[I0][3]); \
    acc[(I0)+1][0] = mfma16(a11, bf[0][1], acc[(I0)+1][0]); \
    acc[(I0)+1][1] = mfma16(a11, bf[1][1], acc[(I0)+1][1]); \
    acc[(I0)+1][2] = mfma16(a11, bf[2][1], acc[(I0)+1][2]); \
    acc[(I0)+1][3] = mfma16(a11, bf[3][1], acc[(I0)+1][3]); \
    __builtin_amdgcn_s_setprio(0); \
    VM; \
    BARR(); \
} while (0)

    // prologue: tile0 A+B, tile1 B; wait tile0 landed (leave tile1.B in flight)
    STG_A(0, 0, 0); STG_A(0, 1, 0); STG_B(0, 0, 0); STG_B(0, 1, 0);
    STG_B(1, 0, 1); STG_B(1, 1, 1);
    VM4;
    BARR();

    for (int it = 0; it < 7; ++it) {
        const int T = 2 * it;
        PHASE(0, 0, 1, STG_A(1, 0, T + 1), VMN);
        PHASE(0, 2, 0, STG_A(1, 1, T + 1), VMN);
        PHASE(0, 4, 0, STG_B(0, 0, T + 2), VMN);
        PHASE(0, 6, 0, STG_B(0, 1, T + 2), VM4);
        PHASE(1, 0, 1, STG_A(0, 0, T + 2), VMN);
        PHASE(1, 2, 0, STG_A(0, 1, T + 2), VMN);
        PHASE(1, 4, 0, STG_B(1, 0, T + 3), VMN);
        PHASE(1, 6, 0, STG_B(1, 1, T + 3), VM4);
    }
    // final iteration (tiles 14, 15): only T+1.A stages remain
    PHASE(0, 0, 1, STG_A(1, 0, 15), VMN);
    PHASE(0, 2, 0, STG_A(1, 1, 15), VMN);
    PHASE(0, 4, 0, VMN, VMN);
    PHASE(0, 6, 0, VMN, VM0);
    PHASE(1, 0, 1, VMN, VMN);
    PHASE(1, 2, 0, VMN, VMN);
    PHASE(1, 4, 0, VMN, VMN);
    PHASE(1, 6, 0, VMN, VMN);

    __syncthreads();   // main-loop LDS reads done before epilogue overwrite
    const int b = m0 >> 11;            // 256-row panels never straddle batch

    if (n0 < 1024) {
        // ---- Q: 4 rounds x 16 units x 1024 el; scale = 0.125*log2(e) ----
        const int h0 = n0 >> 6, qt0 = (m0 & 2047) >> 4;
        #pragma unroll
        for (int c = 0; c < 4; ++c) {
            #pragma unroll
            for (int j = 0; j < 4; ++j) {
                float bv = bias[n0 + wc * 64 + j * 16 + l16];
                int half = j >> 1, qd = (j & 1) * 16 + l16;
                int obase = (wc * 4 + wr * 2) * 1024 + half * 512 +
                            (qd >> 3) * 128 + quad * 32 + (qd & 7);
                #pragma unroll
                for (int li = 0; li < 2; ++li) {
                    int ob = obase + li * 1024;
                    #pragma unroll
                    for (int r = 0; r < 4; ++r)
                        L_[ob + r * 8] = f2bf((acc[2 * c + li][j][r] + bv) * 0.180336880f);
                }
            }
            __syncthreads();
            #pragma unroll
            for (int kk = 0; kk < 4; ++kk) {
                int u = t + 512 * kk;
                int unit = u >> 7, within = u & 127;
                int wcp = unit >> 2, slot = unit & 3;         // slot = wr*2+li
                int qt = qt0 + (slot >> 1) * 8 + c * 2 + (slot & 1);
                int bh = b * 16 + h0 + wcp;
                *(uint4*)(qp + (size_t)(bh * 128 + qt) * 1024 + within * 8) =
                    *(const uint4*)(L_ + u * 8);
            }
            __syncthreads();
        }
    } else if (n0 < 2048) {
        // ---- K: 4 rounds x 8 units x 2048 el ----
        const int h0 = (n0 - 1024) >> 6, tile0 = (m0 & 2047) >> 5;
        const int f2 = (quad & 1) * 2, qh = 4 * (quad >> 1);
        #pragma unroll
        for (int c = 0; c < 4; ++c) {
            #pragma unroll
            for (int j = 0; j < 4; ++j) {
                float bv = bias[n0 + wc * 64 + j * 16 + l16];
                int d = j * 16 + l16;
                int fbit0 = d >> 5, qd = d & 31;
                int obase = (wc * 2 + wr) * 2048 + (f2 | fbit0) * 512 +
                            (qd >> 3) * 128 + qh * 8 + (qd & 7);
                #pragma unroll
                for (int li = 0; li < 2; ++li) {
                    int ob = obase + li * 64;                 // l16k += 8 per li
                    #pragma unroll
                    for (int r = 0; r < 4; ++r)
                        L_[ob + r * 8] = f2bf(acc[2 * c + li][j][r] + bv);
                }
            }
            __syncthreads();
            #pragma unroll
            for (int kk = 0; kk < 4; ++kk) {
                int u = t + 512 * kk;
                int unit = u >> 8, within = u & 255;
                int wcp = unit >> 1, wrp = unit & 1;
                int bh = b * 16 + h0 + wcp;
                int tile = tile0 + wrp * 4 + c;
                *(uint4*)(kvp + (size_t)(bh * 64 + tile) * 4096 + within * 8) =
                    *(const uint4*)(L_ + u * 8);
            }
            __syncthreads();
        }
    } else {
        // ---- V: 4 rounds x 8 units x 2048 el; 4 consecutive elems pack per 8B write ----
        const int h0 = (n0 - 2048) >> 6, tile0 = (m0 & 2047) >> 5;
        const int kr = quad >> 1, e4 = (quad & 1) * 4;
        #pragma unroll
        for (int c = 0; c < 4; ++c) {
            #pragma unroll
            for (int j = 0; j < 4; ++j) {
                float bv = bias[n0 + wc * 64 + j * 16 + l16];
                int obase = (wc * 2 + wr) * 2048 + j * 512 + (kr * 16 + l16) * 8 + e4;
                #pragma unroll
                for (int li = 0; li < 2; ++li) {
                    int ob = obase + li * 256;                // key>>3 += 2 per li
                    unsigned short tmp[4];
                    #pragma unroll
                    for (int r = 0; r < 4; ++r) tmp[r] = f2bf(acc[2 * c + li][j][r] + bv);
                    *(unsigned long long*)(L_ + ob) = *(const unsigned long long*)tmp;
                }
            }
            __syncthreads();
            #pragma unroll
            for (int kk = 0; kk < 4; ++kk) {
                int u = t + 512 * kk;
                int unit = u >> 8, within = u & 255;
                int wcp = unit >> 1, wrp = unit & 1;
                int bh = b * 16 + h0 + wcp;
                int tile = tile0 + wrp * 4 + c;
                *(uint4*)(kvp + (size_t)(bh * 64 + tile) * 4096 + 2048 + within * 8) =
                    *(const uint4*)(L_ + u * 8);
            }
            __syncthreads();
        }
    }
#undef STG_A
#undef STG_B
#undef LDA0
#undef LDA1
#undef LDB0
#undef LDB1
#undef FEN
#undef BARR
#undef VM4
#undef VM0
#undef VMN
#undef PHASE
}

// ---------- causal flash attention v2: 128 queries/block, query-split waves, ----------
// KV staged once to LDS per block (2-phase gl_lds dbuf) and shared by all 4 waves.
// Halves global KV traffic (270->136 MB); no cross-wave merge (each wave owns its rows).
__global__ __launch_bounds__(256) void attn_kernel(const unsigned short* __restrict__ qp,
                                                   const unsigned short* __restrict__ kvp,
                                                   unsigned short* __restrict__ out) {
    const int S = 2048, E = 1024;
    const int wavei = threadIdx.x >> 6;
    const int lane = threadIdx.x & 63;
    const int l16 = lane & 15, quad = lane >> 4;
    const int bidx = blockIdx.x;                         // 0..511
    const int bh = (bidx & 7) * 4 + ((bidx >> 3) & 3);   // 4 bh per XCD
    const int p = 15 - (bidx >> 5);                      // heavy 128q-tiles first
    const int b = bh >> 4, h = bh & 15;
    const int loff = lane * 8;

    // wave handles q rows [qrow0, qrow0+31]; 16-row q-tiles qt0, qt0+1
    const int qt0 = 8 * p + 2 * wavei;
    const int qrow0 = p * 128 + wavei * 32;
    const int cmax = (qrow0 + 31) >> 6;    // this wave's last (straddle) chunk
    const int nch = 2 * p + 2;             // chunks staged by the block

    bf16x8 bq[2][2];
    #pragma unroll
    for (int g = 0; g < 2; ++g)
        #pragma unroll
        for (int hh = 0; hh < 2; ++hh)
            bq[g][hh] = ld8(qp + (size_t)(bh * 128 + qt0 + g) * 1024 + hh * 512 + loff);

    ushort8v ov;
    #pragma unroll
    for (int j = 0; j < 8; ++j) ov[j] = 0x3F80;   // bf16 1.0
    const bf16x8 ones = __builtin_bit_cast(bf16x8, ov);

    f32x4 O[2][4] = {};
    f32x4 Lg[2] = {};
    const unsigned short* tb = kvp + (size_t)bh * 64 * 4096;

    __shared__ __align__(16) unsigned short KV[2][8192];   // 32 KB dbuf (16 KB/chunk)

#define STAGE(C, BUFI) do { \
    const unsigned short* s_ = tb + (size_t)(C) * 8192; \
    _Pragma("unroll") \
    for (int j_ = 0; j_ < 4; ++j_) \
        gl_lds16(s_ + (threadIdx.x + 256 * j_) * 8, KV[BUFI] + (threadIdx.x + 256 * j_) * 8); \
} while (0)

    STAGE(0, 0);
    asm volatile("s_waitcnt vmcnt(0)" ::: "memory");
    __syncthreads();

    for (int c = 0; c < nch; ++c) {
        const int cur = c & 1;
        if (c + 1 < nch) STAGE(c + 1, cur ^ 1);   // issue next-chunk loads first
        if (c <= cmax) {
            const unsigned short* cb = KV[cur];
            const bool maskc = (c == cmax);
            #pragma unroll
            for (int tile = 0; tile < 2; ++tile) {
                const unsigned short* g8 = cb + tile * 4096;
                const int kst = c * 64 + tile * 32;

                bf16x8 k0 = ld8(g8 + 0 * 512 + loff);
                bf16x8 k1 = ld8(g8 + 1 * 512 + loff);
                bf16x8 k2 = ld8(g8 + 2 * 512 + loff);
                bf16x8 k3 = ld8(g8 + 3 * 512 + loff);

                f32x4 s0[2], s1[2];
                #pragma unroll
                for (int g = 0; g < 2; ++g) { s0[g] = {}; s1[g] = {}; }
                #pragma unroll
                for (int g = 0; g < 2; ++g) {
                    s0[g] = mfma16(k0, bq[g][0], s0[g]);
                    s0[g] = mfma16(k1, bq[g][1], s0[g]);
                    s1[g] = mfma16(k2, bq[g][0], s1[g]);
                    s1[g] = mfma16(k3, bq[g][1], s1[g]);
                }

                bf16x8 bp[2];
                #pragma unroll
                for (int g = 0; g < 2; ++g) {
                    float p0[4], p1[4];
                    if (maskc) {
                        const int qg = qrow0 + 16 * g + l16;
                        #pragma unroll
                        for (int r = 0; r < 4; ++r) {
                            int kk = kst + quad * 8 + r;
                            p0[r] = (kk > qg)     ? 0.f : __builtin_amdgcn_exp2f(s0[g][r]);
                            p1[r] = (kk + 4 > qg) ? 0.f : __builtin_amdgcn_exp2f(s1[g][r]);
                        }
                    } else {
                        #pragma unroll
                        for (int r = 0; r < 4; ++r) {
                            p0[r] = __builtin_amdgcn_exp2f(s0[g][r]);
                            p1[r] = __builtin_amdgcn_exp2f(s1[g][r]);
                        }
                    }
                    uint4 pw;
                    pw.x = pk2t(p0[0], p0[1]);
                    pw.y = pk2t(p0[2], p0[3]);
                    pw.z = pk2t(p1[0], p1[1]);
                    pw.w = pk2t(p1[2], p1[3]);
                    bp[g] = __builtin_bit_cast(bf16x8, pw);
                }

                bf16x8 v0 = ld8(g8 + 2048 + 0 * 512 + loff);
                bf16x8 v1 = ld8(g8 + 2048 + 1 * 512 + loff);
                bf16x8 v2 = ld8(g8 + 2048 + 2 * 512 + loff);
                bf16x8 v3 = ld8(g8 + 2048 + 3 * 512 + loff);
                #pragma unroll
                for (int g = 0; g < 2; ++g) {
                    O[g][0] = mfma16(v0, bp[g], O[g][0]);
                    O[g][1] = mfma16(v1, bp[g], O[g][1]);
                    O[g][2] = mfma16(v2, bp[g], O[g][2]);
                    O[g][3] = mfma16(v3, bp[g], O[g][3]);
                    Lg[g]   = mfma16(ones, bp[g], Lg[g]);
                }
            }
        }
        __syncthreads();   // drains the in-flight STAGE (vmcnt0 before barrier)
    }
#undef STAGE

    // epilogue: per-wave LDS transpose (stride 68 pad), then coalesced stores.
    // Each wave uses its own region of the (now dead) KV buffer; no sync needed.
    unsigned short* ST = &KV[0][0] + wavei * 2176;   // 32*68 per wave
    #pragma unroll
    for (int g = 0; g < 2; ++g) {
        const float invl = 1.0f / Lg[g][0];
        #pragma unroll
        for (int tn = 0; tn < 4; ++tn) {
            unsigned short tmp[4];
            #pragma unroll
            for (int r = 0; r < 4; ++r) tmp[r] = f2bf(O[g][tn][r] * invl);
            // q = 16g + l16, d = tn*16 + quad*4 .. +3   (8B store, stride-68 rows)
            *(unsigned long long*)(ST + (16 * g + l16) * 68 + tn * 16 + quad * 4) =
                *(const unsigned long long*)tmp;
        }
    }
    // no barrier: each wave reads only its own region
    const size_t rbase = (size_t)(b * S + p * 128 + wavei * 32) * E + h * 64;
    #pragma unroll
    for (int it = 0; it < 4; ++it) {
        int idx = lane + 64 * it;          // 0..255
        int qq = idx >> 3, dg = idx & 7;
        *(uint4*)(out + rbase + (size_t)qq * E + dg * 8) =
            *(const uint4*)(ST + qq * 68 + dg * 8);
    }
}

// ---------- launcher ----------
extern "C" void kernel_launch(void* const* d_in, const int* in_sizes, int n_in,
                              void* d_out, int out_size, void* d_ws, size_t ws_size,
                              hipStream_t stream) {
    const float* x     = (const float*)d_in[0];
    const float* qkv_w = (const float*)d_in[1];
    const float* qkv_b = (const float*)d_in[2];
    const float* out_w = (const float*)d_in[3];
    const float* out_b = (const float*)d_in[4];
    float* out = (float*)d_out;

    const int B = 2, S = 2048, E = 1024;
    const int M = B * S;        // 4096
    const int N1 = 3 * E;       // 3072

    unsigned short* ws    = (unsigned short*)d_ws;
    unsigned short* xb    = ws;
    unsigned short* w1b   = xb   + (size_t)M * E;
    unsigned short* w2b   = w1b  + (size_t)N1 * E;
    unsigned short* qpb   = w2b  + (size_t)E * E;
    unsigned short* kvpb  = qpb  + (size_t)32 * 128 * 1024;
    unsigned short* attnb = kvpb + (size_t)32 * 64 * 4096;

    cvt3<<<dim3(8192), dim3(256), 0, stream>>>(x, qkv_w, out_w, xb, w1b, w2b);

    gemm_qkv<<<dim3(N1 / 256, M / 256), dim3(512), 0, stream>>>(
        xb, w1b, qkv_b, qpb, kvpb, M, N1, E);

    attn_kernel<<<dim3(512), dim3(256), 0, stream>>>(qpb, kvpb, attnb);

    gemm_out<<<dim3(E / 128, M / 64), dim3(256), 0, stream>>>(
        attnb, w2b, out_b, out, M, E, E);
}

// Round 6
// 160.661 us; speedup vs baseline: 1.1243x; 1.1243x over previous
//
#include <hip/hip_runtime.h>
#include <cmath>

// ---------- types & helpers ----------
typedef __attribute__((ext_vector_type(8))) __bf16 bf16x8;
typedef __attribute__((ext_vector_type(8))) unsigned short ushort8v;
typedef __attribute__((ext_vector_type(4))) float f32x4;

__device__ inline unsigned short f2bf(float f) {
    unsigned int u = __float_as_uint(f);
    unsigned int r = (u + 0x7fffu + ((u >> 16) & 1u)) >> 16;   // RNE
    return (unsigned short)r;
}

__device__ inline bf16x8 ld8(const unsigned short* p) {
    uint4 v = *(const uint4*)p;
    return __builtin_bit_cast(bf16x8, v);
}

__device__ inline f32x4 mfma16(bf16x8 a, bf16x8 b, f32x4 c) {
    return __builtin_amdgcn_mfma_f32_16x16x32_bf16(a, b, c, 0, 0, 0);
}

// truncating pack: low16 = hi16(a), high16 = hi16(b)  (1 v_perm_b32)
__device__ inline unsigned pk2t(float a, float b) {
    return __builtin_amdgcn_perm(__float_as_uint(b), __float_as_uint(a), 0x07060302u);
}

// async global->LDS, 16B per lane.
__device__ inline void gl_lds16(const unsigned short* g, const unsigned short* l) {
    __builtin_amdgcn_global_load_lds(
        (const __attribute__((address_space(1))) void*)(unsigned long long)g,
        (__attribute__((address_space(3))) void*)(unsigned)(unsigned long long)l,
        16, 0, 0);
}

// ---------- fused fp32 -> bf16 convert (x and qkv_w only; out_w handled by gemm_qkv tail blocks) ----------
#define NX4  1048576   // M*E/4
#define NW14 786432    // N1*E/4
__global__ __launch_bounds__(256) void cvt2(const float* __restrict__ x,
                                            const float* __restrict__ w1,
                                            unsigned short* __restrict__ xb,
                                            unsigned short* __restrict__ w1b) {
    int i = blockIdx.x * 256 + threadIdx.x;    // grid 7168 -> exactly NX4+NW14 threads
    const float* src;
    unsigned short* dst;
    int off;
    if (i < NX4) { src = x;  dst = xb;  off = i; }
    else         { src = w1; dst = w1b; off = i - NX4; }
    float4 v = ((const float4*)src)[off];
    ushort4 o;
    o.x = f2bf(v.x); o.y = f2bf(v.y); o.z = f2bf(v.z); o.w = f2bf(v.w);
    ((ushort4*)dst)[off] = o;
}

// ---------- out-proj GEMM: C[M,N] = A@B^T + bias, fp32 out ----------
__global__ __launch_bounds__(256) void gemm_out(const unsigned short* __restrict__ A,
                                                const unsigned short* __restrict__ B,
                                                const float* __restrict__ bias,
                                                float* __restrict__ C,
                                                int M, int N, int K) {
    __shared__ __align__(16) unsigned short As0[64 * 32];
    __shared__ __align__(16) unsigned short Bs0[128 * 32];
    __shared__ __align__(16) unsigned short As1[64 * 32];
    __shared__ __align__(16) unsigned short Bs1[128 * 32];
    const int m0 = blockIdx.y * 64;
    const int n0 = blockIdx.x * 128;
    const int t = threadIdx.x;
    const int wave = t >> 6, lane = t & 63;
    const int l16 = lane & 15, quad = lane >> 4;
    const int wm = (wave >> 1) * 32, wn = (wave & 1) * 64;

    f32x4 acc[2][4] = {};

    const int ra = t >> 2, ka = (t & 3) * 8;
    const int b1 = 256 + t;
    const int rb0 = t >> 2, kb0 = (t & 3) * 8;
    const int rb1 = b1 >> 2, kb1 = (b1 & 3) * 8;

    for (int k0 = 0; k0 < K; k0 += 64) {
        __syncthreads();
        gl_lds16(A + (size_t)(m0 + ra) * K + k0 + ka,        As0 + t * 8);
        gl_lds16(B + (size_t)(n0 + rb0) * K + k0 + kb0,      Bs0 + t * 8);
        gl_lds16(B + (size_t)(n0 + rb1) * K + k0 + kb1,      Bs0 + b1 * 8);
        gl_lds16(A + (size_t)(m0 + ra) * K + k0 + 32 + ka,   As1 + t * 8);
        gl_lds16(B + (size_t)(n0 + rb0) * K + k0 + 32 + kb0, Bs1 + t * 8);
        gl_lds16(B + (size_t)(n0 + rb1) * K + k0 + 32 + kb1, Bs1 + b1 * 8);
        __syncthreads();

        bf16x8 af[2], bfr[4];
        #pragma unroll
        for (int i = 0; i < 2; ++i)
            af[i] = ld8(As0 + (wm + i * 16 + l16) * 32 + quad * 8);
        #pragma unroll
        for (int j = 0; j < 4; ++j)
            bfr[j] = ld8(Bs0 + (wn + j * 16 + l16) * 32 + quad * 8);
        #pragma unroll
        for (int i = 0; i < 2; ++i)
            #pragma unroll
            for (int j = 0; j < 4; ++j)
                acc[i][j] = mfma16(af[i], bfr[j], acc[i][j]);

        #pragma unroll
        for (int i = 0; i < 2; ++i)
            af[i] = ld8(As1 + (wm + i * 16 + l16) * 32 + quad * 8);
        #pragma unroll
        for (int j = 0; j < 4; ++j)
            bfr[j] = ld8(Bs1 + (wn + j * 16 + l16) * 32 + quad * 8);
        #pragma unroll
        for (int i = 0; i < 2; ++i)
            #pragma unroll
            for (int j = 0; j < 4; ++j)
                acc[i][j] = mfma16(af[i], bfr[j], acc[i][j]);
    }

    #pragma unroll
    for (int i = 0; i < 2; ++i) {
        #pragma unroll
        for (int j = 0; j < 4; ++j) {
            int col = n0 + wn + j * 16 + l16;
            float bv = bias[col];
            #pragma unroll
            for (int r = 0; r < 4; ++r) {
                int row = m0 + wm + i * 16 + quad * 4 + r;
                C[(size_t)row * N + col] = acc[i][j][r] + bv;
            }
        }
    }
}

// ---------- QKV GEMM: 256x256 tile, 8-phase counted-vmcnt schedule (T2+T3+T4+T5) ----------
// Grid is 13x16: x<12 = 192 GEMM blocks (75% of 256 CUs); x==12 = 16 tail blocks that
// convert out_w fp32->bf16 on the otherwise-idle CUs (w2b consumed only by gemm_out later).
__global__ __launch_bounds__(512, 1) void gemm_qkv(const unsigned short* __restrict__ A,
                                                   const unsigned short* __restrict__ B,
                                                   const float* __restrict__ bias,
                                                   unsigned short* __restrict__ qp,
                                                   unsigned short* __restrict__ kvp,
                                                   const float* __restrict__ w2,
                                                   unsigned short* __restrict__ w2b,
                                                   int M, int N, int K) {
    if (blockIdx.x == 12) {
        // tail blocks: 16 blocks x 512 threads convert E*E/4 = 262144 float4s
        int tid = blockIdx.y * 512 + threadIdx.x;
        #pragma unroll 4
        for (int i = tid; i < 262144; i += 8192) {
            float4 v = ((const float4*)w2)[i];
            ushort4 o;
            o.x = f2bf(v.x); o.y = f2bf(v.y); o.z = f2bf(v.z); o.w = f2bf(v.w);
            ((ushort4*)w2b)[i] = o;
        }
        return;
    }
    __shared__ __align__(16) unsigned short L_[65536];   // 128 KB
    const int m0 = blockIdx.y * 256;
    const int n0 = blockIdx.x * 256;
    const int t = threadIdx.x;
    const int wave = t >> 6, lane = t & 63;
    const int l16 = lane & 15, quad = lane >> 4;
    const int wr = wave >> 2, wc = wave & 3;
    const int rswz = (l16 & 7) << 3;     // read-side chunk XOR (elements)

    f32x4 acc[8][4] = {};
    bf16x8 bf[4][2];

    // staging geometry: chunk c -> row c>>3, k-chunk (c&7) XOR (row&7) (pre-swizzled source)
    const int c0 = t, c1 = 512 + t;
    const int r0 = c0 >> 3, k0e = ((c0 & 7) ^ (r0 & 7)) * 8;
    const int r1 = c1 >> 3, k1e = ((c1 & 7) ^ (r1 & 7)) * 8;
    const unsigned short* Ab0 = A + (size_t)(m0 + r0) * 1024 + k0e;
    const unsigned short* Ab1 = A + (size_t)(m0 + r1) * 1024 + k1e;
    const unsigned short* Bb0 = B + (size_t)(n0 + r0) * 1024 + k0e;
    const unsigned short* Bb1 = B + (size_t)(n0 + r1) * 1024 + k1e;
    unsigned short* Ld0 = L_ + c0 * 8;
    unsigned short* Ld1 = L_ + c1 * 8;

#define STG_A(par, h, T_) do { \
    gl_lds16(Ab0 + (h) * 131072 + (T_) * 64, Ld0 + (par) * 16384 + (h) * 8192); \
    gl_lds16(Ab1 + (h) * 131072 + (T_) * 64, Ld1 + (par) * 16384 + (h) * 8192); } while (0)
#define STG_B(par, h, T_) do { \
    gl_lds16(Bb0 + (h) * 131072 + (T_) * 64, Ld0 + 32768 + (par) * 16384 + (h) * 8192); \
    gl_lds16(Bb1 + (h) * 131072 + (T_) * 64, Ld1 + 32768 + (par) * 16384 + (h) * 8192); } while (0)

    // fragment read bases (swizzled reads)
    const unsigned short* Afr = L_ + wr * 8192 + l16 * 64;
    const unsigned short* Bfr = L_ + 32768 + (wc >> 1) * 8192 + ((wc & 1) * 64 + l16) * 64;
    const int koff0 = (quad * 8) ^ rswz;
    const int koff1 = (32 + quad * 8) ^ rswz;

#define LDA0(dst, par, i_) dst = ld8(Afr + (par) * 16384 + (i_) * 1024 + koff0)
#define LDA1(dst, par, i_) dst = ld8(Afr + (par) * 16384 + (i_) * 1024 + koff1)
#define LDB0(dst, par, j_) dst = ld8(Bfr + (par) * 16384 + (j_) * 1024 + koff0)
#define LDB1(dst, par, j_) dst = ld8(Bfr + (par) * 16384 + (j_) * 1024 + koff1)

#define FEN() asm volatile("" ::: "memory")
#define BARR() do { FEN(); __builtin_amdgcn_s_barrier(); FEN(); } while (0)
#define VM4 asm volatile("s_waitcnt vmcnt(4)" ::: "memory")
#define VM0 asm volatile("s_waitcnt vmcnt(0)" ::: "memory")
#define VMN ((void)0)

#define PHASE(PAR, I0, LOADB, STG, VM) do { \
    bf16x8 a00, a01, a10, a11; \
    if (LOADB) { \
        LDB0(bf[0][0], PAR, 0); LDB1(bf[0][1], PAR, 0); \
        LDB0(bf[1][0], PAR, 1); LDB1(bf[1][1], PAR, 1); \
        LDB0(bf[2][0], PAR, 2); LDB1(bf[2][1], PAR, 2); \
        LDB0(bf[3][0], PAR, 3); LDB1(bf[3][1], PAR, 3); \
    } \
    LDA0(a00, PAR, I0); LDA1(a01, PAR, I0); \
    LDA0(a10, PAR, (I0) + 1); LDA1(a11, PAR, (I0) + 1); \
    STG; \
    BARR(); \
    __builtin_amdgcn_s_setprio(1); \
    acc[I0][0] = mfma16(a00, bf[0][0], acc[I0][0]); \
    acc[I0][1] = mfma16(a00, bf[1][0], acc[I0][1]); \
    acc[I0][2] = mfma16(a00, bf[2][0], acc[I0][2]); \
    acc[I0][3] = mfma16(a00, bf[3][0], acc[I0][3]); \
    acc[(I0)+1][0] = mfma16(a10, bf[0][0], acc[(I0)+1][0]); \
    acc[(I0)+1][1] = mfma16(a10, bf[1][0], acc[(I0)+1][1]); \
    acc[(I0)+1][2] = mfma16(a10, bf[2][0], acc[(I0)+1][2]); \
    acc[(I0)+1][3] = mfma16(a10, bf[3][0], acc[(I0)+1][3]); \
    acc[I0][0] = mfma16(a01, bf[0][1], acc[I0][0]); \
    acc[I0][1] = mfma16(a01, bf[1][1], acc[I0][1]); \
    acc[I0][2] = mfma16(a01, bf[2][1], acc[I0][2]); \
    acc[I0][3] = mfma16(a01, bf[3][1], acc[I0][3]); \
    acc[(I0)+1][0] = mfma16(a11, bf[0][1], acc[(I0)+1][0]); \
    acc[(I0)+1][1] = mfma16(a11, bf[1][1], acc[(I0)+1][1]); \
    acc[(I0)+1][2] = mfma16(a11, bf[2][1], acc[(I0)+1][2]); \
    acc[(I0)+1][3] = mfma16(a11, bf[3][1], acc[(I0)+1][3]); \
    __builtin_amdgcn_s_setprio(0); \
    VM; \
    BARR(); \
} while (0)

    // prologue: tile0 A+B, tile1 B; wait tile0 landed (leave tile1.B in flight)
    STG_A(0, 0, 0); STG_A(0, 1, 0); STG_B(0, 0, 0); STG_B(0, 1, 0);
    STG_B(1, 0, 1); STG_B(1, 1, 1);
    VM4;
    BARR();

    for (int it = 0; it < 7; ++it) {
        const int T = 2 * it;
        PHASE(0, 0, 1, STG_A(1, 0, T + 1), VMN);
        PHASE(0, 2, 0, STG_A(1, 1, T + 1), VMN);
        PHASE(0, 4, 0, STG_B(0, 0, T + 2), VMN);
        PHASE(0, 6, 0, STG_B(0, 1, T + 2), VM4);
        PHASE(1, 0, 1, STG_A(0, 0, T + 2), VMN);
        PHASE(1, 2, 0, STG_A(0, 1, T + 2), VMN);
        PHASE(1, 4, 0, STG_B(1, 0, T + 3), VMN);
        PHASE(1, 6, 0, STG_B(1, 1, T + 3), VM4);
    }
    // final iteration (tiles 14, 15): only T+1.A stages remain
    PHASE(0, 0, 1, STG_A(1, 0, 15), VMN);
    PHASE(0, 2, 0, STG_A(1, 1, 15), VMN);
    PHASE(0, 4, 0, VMN, VMN);
    PHASE(0, 6, 0, VMN, VM0);
    PHASE(1, 0, 1, VMN, VMN);
    PHASE(1, 2, 0, VMN, VMN);
    PHASE(1, 4, 0, VMN, VMN);
    PHASE(1, 6, 0, VMN, VMN);

    __syncthreads();   // main-loop LDS reads done before epilogue overwrite
    const int b = m0 >> 11;            // 256-row panels never straddle batch

    if (n0 < 1024) {
        // ---- Q: 4 rounds x 16 units x 1024 el; scale = 0.125*log2(e) ----
        const int h0 = n0 >> 6, qt0 = (m0 & 2047) >> 4;
        #pragma unroll
        for (int c = 0; c < 4; ++c) {
            #pragma unroll
            for (int j = 0; j < 4; ++j) {
                float bv = bias[n0 + wc * 64 + j * 16 + l16];
                int half = j >> 1, qd = (j & 1) * 16 + l16;
                int obase = (wc * 4 + wr * 2) * 1024 + half * 512 +
                            (qd >> 3) * 128 + quad * 32 + (qd & 7);
                #pragma unroll
                for (int li = 0; li < 2; ++li) {
                    int ob = obase + li * 1024;
                    #pragma unroll
                    for (int r = 0; r < 4; ++r)
                        L_[ob + r * 8] = f2bf((acc[2 * c + li][j][r] + bv) * 0.180336880f);
                }
            }
            __syncthreads();
            #pragma unroll
            for (int kk = 0; kk < 4; ++kk) {
                int u = t + 512 * kk;
                int unit = u >> 7, within = u & 127;
                int wcp = unit >> 2, slot = unit & 3;         // slot = wr*2+li
                int qt = qt0 + (slot >> 1) * 8 + c * 2 + (slot & 1);
                int bh = b * 16 + h0 + wcp;
                *(uint4*)(qp + (size_t)(bh * 128 + qt) * 1024 + within * 8) =
                    *(const uint4*)(L_ + u * 8);
            }
            __syncthreads();
        }
    } else if (n0 < 2048) {
        // ---- K: 4 rounds x 8 units x 2048 el ----
        const int h0 = (n0 - 1024) >> 6, tile0 = (m0 & 2047) >> 5;
        const int f2 = (quad & 1) * 2, qh = 4 * (quad >> 1);
        #pragma unroll
        for (int c = 0; c < 4; ++c) {
            #pragma unroll
            for (int j = 0; j < 4; ++j) {
                float bv = bias[n0 + wc * 64 + j * 16 + l16];
                int d = j * 16 + l16;
                int fbit0 = d >> 5, qd = d & 31;
                int obase = (wc * 2 + wr) * 2048 + (f2 | fbit0) * 512 +
                            (qd >> 3) * 128 + qh * 8 + (qd & 7);
                #pragma unroll
                for (int li = 0; li < 2; ++li) {
                    int ob = obase + li * 64;                 // l16k += 8 per li
                    #pragma unroll
                    for (int r = 0; r < 4; ++r)
                        L_[ob + r * 8] = f2bf(acc[2 * c + li][j][r] + bv);
                }
            }
            __syncthreads();
            #pragma unroll
            for (int kk = 0; kk < 4; ++kk) {
                int u = t + 512 * kk;
                int unit = u >> 8, within = u & 255;
                int wcp = unit >> 1, wrp = unit & 1;
                int bh = b * 16 + h0 + wcp;
                int tile = tile0 + wrp * 4 + c;
                *(uint4*)(kvp + (size_t)(bh * 64 + tile) * 4096 + within * 8) =
                    *(const uint4*)(L_ + u * 8);
            }
            __syncthreads();
        }
    } else {
        // ---- V: 4 rounds x 8 units x 2048 el; 4 consecutive elems pack per 8B write ----
        const int h0 = (n0 - 2048) >> 6, tile0 = (m0 & 2047) >> 5;
        const int kr = quad >> 1, e4 = (quad & 1) * 4;
        #pragma unroll
        for (int c = 0; c < 4; ++c) {
            #pragma unroll
            for (int j = 0; j < 4; ++j) {
                float bv = bias[n0 + wc * 64 + j * 16 + l16];
                int obase = (wc * 2 + wr) * 2048 + j * 512 + (kr * 16 + l16) * 8 + e4;
                #pragma unroll
                for (int li = 0; li < 2; ++li) {
                    int ob = obase + li * 256;                // key>>3 += 2 per li
                    unsigned short tmp[4];
                    #pragma unroll
                    for (int r = 0; r < 4; ++r) tmp[r] = f2bf(acc[2 * c + li][j][r] + bv);
                    *(unsigned long long*)(L_ + ob) = *(const unsigned long long*)tmp;
                }
            }
            __syncthreads();
            #pragma unroll
            for (int kk = 0; kk < 4; ++kk) {
                int u = t + 512 * kk;
                int unit = u >> 8, within = u & 255;
                int wcp = unit >> 1, wrp = unit & 1;
                int bh = b * 16 + h0 + wcp;
                int tile = tile0 + wrp * 4 + c;
                *(uint4*)(kvp + (size_t)(bh * 64 + tile) * 4096 + 2048 + within * 8) =
                    *(const uint4*)(L_ + u * 8);
            }
            __syncthreads();
        }
    }
#undef STG_A
#undef STG_B
#undef LDA0
#undef LDA1
#undef LDB0
#undef LDB1
#undef FEN
#undef BARR
#undef VM4
#undef VM0
#undef VMN
#undef PHASE
}

// ---------- causal flash attention: 64 queries/block, 4-way key-split ----------
// (reverted to the proven round-4 version: reg-resident K/V, halved merge buffer)
__global__ __launch_bounds__(256, 2) void attn_kernel(const unsigned short* __restrict__ qp,
                                                      const unsigned short* __restrict__ kvp,
                                                      unsigned short* __restrict__ out) {
    const int S = 2048, E = 1024;
    const int wavei = threadIdx.x >> 6;
    const int lane = threadIdx.x & 63;
    const int l16 = lane & 15, quad = lane >> 4;
    const int bidx = blockIdx.x;                         // 0..1023
    const int bh = (bidx & 7) * 4 + ((bidx >> 3) & 3);   // 4 bh per XCD
    const int P = 31 - (bidx >> 5);                      // heavy 64q-tiles first
    const int b = bh >> 4, h = bh & 15;
    const int loff = lane * 8;

    const unsigned short* qbase = qp + (size_t)(bh * 128 + 4 * P) * 1024;
    bf16x8 bq[4][2];
    #pragma unroll
    for (int g = 0; g < 4; ++g) {
        bq[g][0] = ld8(qbase + (2 * g) * 512 + loff);
        bq[g][1] = ld8(qbase + (2 * g + 1) * 512 + loff);
    }

    ushort8v ov;
    #pragma unroll
    for (int j = 0; j < 8; ++j) ov[j] = 0x3F80;   // bf16 1.0
    const bf16x8 ones = __builtin_bit_cast(bf16x8, ov);

    f32x4 O[4][4] = {};           // [group][tn]
    f32x4 L[4] = {};
    const int nchunks = P + 1;
    const unsigned short* tbase = kvp + (size_t)bh * 64 * 4096;

    for (int c = wavei; c < nchunks; c += 4) {
        const unsigned short* tb = tbase + (size_t)c * 8192;
        bf16x8 f[16];
        #pragma unroll
        for (int i = 0; i < 16; ++i) f[i] = ld8(tb + i * 512 + loff);

        const bool lastc = (c == nchunks - 1);
        const int ks = c * 64;

        #pragma unroll
        for (int tile = 0; tile < 2; ++tile) {
            const bf16x8* g8 = f + tile * 8;
            const int kst = ks + tile * 32;

            f32x4 s0[4], s1[4];
            #pragma unroll
            for (int g = 0; g < 4; ++g) { s0[g] = {}; s1[g] = {}; }
            #pragma unroll
            for (int g = 0; g < 4; ++g) {
                s0[g] = mfma16(g8[0], bq[g][0], s0[g]);
                s0[g] = mfma16(g8[1], bq[g][1], s0[g]);
                s1[g] = mfma16(g8[2], bq[g][0], s1[g]);
                s1[g] = mfma16(g8[3], bq[g][1], s1[g]);
            }

            bf16x8 bp[4];
            #pragma unroll
            for (int g = 0; g < 4; ++g) {
                float p0[4], p1[4];
                if (lastc) {
                    const int qg = 64 * P + 16 * g + l16;
                    #pragma unroll
                    for (int r = 0; r < 4; ++r) {
                        int kk = kst + quad * 8 + r;
                        p0[r] = (kk > qg)     ? 0.f : __builtin_amdgcn_exp2f(s0[g][r]);
                        p1[r] = (kk + 4 > qg) ? 0.f : __builtin_amdgcn_exp2f(s1[g][r]);
                    }
                } else {
                    #pragma unroll
                    for (int r = 0; r < 4; ++r) {
                        p0[r] = __builtin_amdgcn_exp2f(s0[g][r]);
                        p1[r] = __builtin_amdgcn_exp2f(s1[g][r]);
                    }
                }
                uint4 pw;
                pw.x = pk2t(p0[0], p0[1]);
                pw.y = pk2t(p0[2], p0[3]);
                pw.z = pk2t(p1[0], p1[1]);
                pw.w = pk2t(p1[2], p1[3]);
                bp[g] = __builtin_bit_cast(bf16x8, pw);
            }

            #pragma unroll
            for (int g = 0; g < 4; ++g) {
                O[g][0] = mfma16(g8[4], bp[g], O[g][0]);
                O[g][1] = mfma16(g8[5], bp[g], O[g][1]);
                O[g][2] = mfma16(g8[6], bp[g], O[g][2]);
                O[g][3] = mfma16(g8[7], bp[g], O[g][3]);
                L[g]    = mfma16(ones, bp[g], L[g]);
            }
        }
    }

    // merge 4 key-split partials (pure sums) through LDS, half-size buffer:
    // waves 0,1 write; waves 2,3 accumulate in place; final pass sums 2 buffers.
    __shared__ float Ob[2][64][66];
    __shared__ float Lb[4][64];
    if (wavei < 2) {
        #pragma unroll
        for (int g = 0; g < 4; ++g)
            #pragma unroll
            for (int tn = 0; tn < 4; ++tn)
                #pragma unroll
                for (int r = 0; r < 4; ++r)
                    Ob[wavei][g * 16 + l16][tn * 16 + quad * 4 + r] = O[g][tn][r];
    }
    #pragma unroll
    for (int g = 0; g < 4; ++g)
        if (quad == 0) Lb[wavei][g * 16 + l16] = L[g][0];
    __syncthreads();
    if (wavei >= 2) {
        #pragma unroll
        for (int g = 0; g < 4; ++g)
            #pragma unroll
            for (int tn = 0; tn < 4; ++tn)
                #pragma unroll
                for (int r = 0; r < 4; ++r)
                    Ob[wavei - 2][g * 16 + l16][tn * 16 + quad * 4 + r] += O[g][tn][r];
    }
    __syncthreads();

    const int t = threadIdx.x;
    const int qi = t >> 2, hg = (t & 3) * 16;
    float ls = Lb[0][qi] + Lb[1][qi] + Lb[2][qi] + Lb[3][qi];
    const float invl = 1.0f / ls;
    const size_t obase = (size_t)(b * S + 64 * P + qi) * E + h * 64;
    #pragma unroll
    for (int part = 0; part < 2; ++part) {
        int hd0 = hg + part * 8;
        unsigned short o[8];
        #pragma unroll
        for (int k = 0; k < 8; ++k) {
            float a = Ob[0][qi][hd0 + k] + Ob[1][qi][hd0 + k];
            o[k] = f2bf(a * invl);
        }
        *(uint4*)(out + obase + hd0) = *(uint4*)o;
    }
}

// ---------- launcher ----------
extern "C" void kernel_launch(void* const* d_in, const int* in_sizes, int n_in,
                              void* d_out, int out_size, void* d_ws, size_t ws_size,
                              hipStream_t stream) {
    const float* x     = (const float*)d_in[0];
    const float* qkv_w = (const float*)d_in[1];
    const float* qkv_b = (const float*)d_in[2];
    const float* out_w = (const float*)d_in[3];
    const float* out_b = (const float*)d_in[4];
    float* out = (float*)d_out;

    const int B = 2, S = 2048, E = 1024;
    const int M = B * S;        // 4096
    const int N1 = 3 * E;       // 3072

    unsigned short* ws    = (unsigned short*)d_ws;
    unsigned short* xb    = ws;
    unsigned short* w1b   = xb   + (size_t)M * E;
    unsigned short* w2b   = w1b  + (size_t)N1 * E;
    unsigned short* qpb   = w2b  + (size_t)E * E;
    unsigned short* kvpb  = qpb  + (size_t)32 * 128 * 1024;
    unsigned short* attnb = kvpb + (size_t)32 * 64 * 4096;

    cvt2<<<dim3(7168), dim3(256), 0, stream>>>(x, qkv_w, xb, w1b);

    gemm_qkv<<<dim3(13, 16), dim3(512), 0, stream>>>(
        xb, w1b, qkv_b, qpb, kvpb, out_w, w2b, M, N1, E);

    attn_kernel<<<dim3(1024), dim3(256), 0, stream>>>(qpb, kvpb, attnb);

    gemm_out<<<dim3(E / 128, M / 64), dim3(256), 0, stream>>>(
        attnb, w2b, out_b, out, M, E, E);
}